// Round 11
// baseline (237.228 us; speedup 1.0000x reference)
//
#include <hip/hip_runtime.h>
#include <math.h>

#define NUM_K 16
#define DELTA_V 0.5f
#define DELTA_D 1.5f

// B=8, N=640*640=409600 px/batch, ng=102400 quads/batch.
// Grid: 200 blocks/batch, 256 thr, 2 quads/thread straight-line.
#define BPB 200
#define QSTRIDE (BPB * 256)

// ws layout (floats), all fully overwritten every launch (no memset needed):
//   stage1 @ 0      : [8][80][200]  per-block pass1 partials (75 rows used)
//   stage2 @ 128000 : [8][32][200]  per-block pass2 partials (30 rows used)
//   meanv  @ 179200 : [8][64]       per-batch means (k*4+d)
#define S1OFF 0
#define S2OFF 128000
#define MVOFF 179200

// ---------------------------------------------------------------------------
// pass1: 16-copy privatized LDS histogram; flush = plain stores to distinct
// staging slots (NO global atomics -> no same-address serialization tail).
// ---------------------------------------------------------------------------
__global__ __launch_bounds__(256) void pass1_kernel(
    const float* __restrict__ emb, const int* __restrict__ inst,
    const float* __restrict__ kern, const float* __restrict__ tmask,
    float* __restrict__ stage1, int N)
{
    __shared__ float s_h[75 * 17];
    for (int i = threadIdx.x; i < 75 * 17; i += 256) s_h[i] = 0.f;
    __syncthreads();

    const int tid  = threadIdx.x;
    const int b    = blockIdx.x / BPB;
    const int wb   = blockIdx.x % BPB;
    const int copy = tid & 15;

    const size_t base = (size_t)b * N;
    const int4*   iv4 = (const int4*)(inst + base);
    const float4* kv4 = (const float4*)(kern + base);
    const float4* tv4 = (const float4*)(tmask + base);
    const float4* e0v = (const float4*)(emb + ((size_t)b * 4 + 0) * N);
    const float4* e1v = (const float4*)(emb + ((size_t)b * 4 + 1) * N);
    const float4* e2v = (const float4*)(emb + ((size_t)b * 4 + 2) * N);
    const float4* e3v = (const float4*)(emb + ((size_t)b * 4 + 3) * N);

    const int g0 = wb * 256 + tid;
    const int g1 = g0 + QSTRIDE;

    const int4   ivA = iv4[g0], ivB = iv4[g1];
    const float4 kvA = kv4[g0], kvB = kv4[g1];
    const float4 tvA = tv4[g0], tvB = tv4[g1];
    const float4 a0A = e0v[g0], a0B = e0v[g1];
    const float4 a1A = e1v[g0], a1B = e1v[g1];
    const float4 a2A = e2v[g0], a2B = e2v[g1];
    const float4 a3A = e3v[g0], a3B = e3v[g1];

    #define ACC1(iv, kv, tv, a0, a1, a2, a3, px)                               \
        {                                                                      \
            const int lab = iv.px;                                             \
            if (lab > 0 && tv.px > 0.5f && kv.px > 0.5f) {                     \
                float* p = &s_h[(lab - 1) * 85 + copy];                        \
                atomicAdd(p +  0, a0.px);                                      \
                atomicAdd(p + 17, a1.px);                                      \
                atomicAdd(p + 34, a2.px);                                      \
                atomicAdd(p + 51, a3.px);                                      \
                atomicAdd(p + 68, 1.f);                                        \
            }                                                                  \
        }
    ACC1(ivA, kvA, tvA, a0A, a1A, a2A, a3A, x)
    ACC1(ivA, kvA, tvA, a0A, a1A, a2A, a3A, y)
    ACC1(ivA, kvA, tvA, a0A, a1A, a2A, a3A, z)
    ACC1(ivA, kvA, tvA, a0A, a1A, a2A, a3A, w)
    ACC1(ivB, kvB, tvB, a0B, a1B, a2B, a3B, x)
    ACC1(ivB, kvB, tvB, a0B, a1B, a2B, a3B, y)
    ACC1(ivB, kvB, tvB, a0B, a1B, a2B, a3B, z)
    ACC1(ivB, kvB, tvB, a0B, a1B, a2B, a3B, w)
    #undef ACC1

    __syncthreads();

    if (tid < 80) {
        float s = 0.f;
        if (tid < 75) {
            #pragma unroll
            for (int c = 0; c < 16; ++c) s += s_h[tid * 17 + c];
        }
        stage1[b * 16000 + tid * 200 + wb] = s;   // distinct slot, plain store
    }
}

// ---------------------------------------------------------------------------
// reduce_means: 8 blocks (one per batch). Row r of stage1 is 200 contiguous
// floats -> coalesced lane reads + wave butterfly. Writes meanv[b][64].
// ---------------------------------------------------------------------------
__global__ __launch_bounds__(256) void reduce_means_kernel(
    const float* __restrict__ stage1, float* __restrict__ meanv)
{
    __shared__ float rs[80];
    const int b = blockIdx.x, tid = threadIdx.x;
    const int w = tid >> 6, lane = tid & 63;

    for (int r = w; r < 80; r += 4) {
        const float* p = stage1 + b * 16000 + r * 200;
        float s = 0.f;
        for (int j = lane; j < 200; j += 64) s += p[j];
        #pragma unroll
        for (int m = 32; m > 0; m >>= 1) s += __shfl_xor(s, m, 64);
        if (lane == 0) rs[r] = s;
    }
    __syncthreads();

    if (tid < 64) {
        const int k = tid >> 2, d = tid & 3;
        float mv = 0.f;
        if (k > 0) {
            const float s = rs[(k - 1) * 5 + d];
            const float c = rs[(k - 1) * 5 + 4];
            mv = s / fmaxf(c, 1.f);
        }
        meanv[b * 64 + tid] = mv;
    }
}

// ---------------------------------------------------------------------------
// pass2: distance-to-mean binning, 16-copy histogram, plain-store flush.
// ---------------------------------------------------------------------------
__global__ __launch_bounds__(256) void pass2_kernel(
    const float* __restrict__ emb, const int* __restrict__ inst,
    const float* __restrict__ tmask, const float* __restrict__ meanv,
    float* __restrict__ stage2, int N)
{
    __shared__ float  s_h[30 * 17];
    __shared__ float4 s_mean[NUM_K];

    for (int i = threadIdx.x; i < 30 * 17; i += 256) s_h[i] = 0.f;

    const int tid = threadIdx.x;
    const int b   = blockIdx.x / BPB;
    const int wb  = blockIdx.x % BPB;

    if (tid < 64) ((float*)&s_mean[0])[tid] = meanv[b * 64 + tid];
    __syncthreads();

    const int copy = tid & 15;

    const size_t base = (size_t)b * N;
    const int4*   iv4 = (const int4*)(inst + base);
    const float4* tv4 = (const float4*)(tmask + base);
    const float4* e0v = (const float4*)(emb + ((size_t)b * 4 + 0) * N);
    const float4* e1v = (const float4*)(emb + ((size_t)b * 4 + 1) * N);
    const float4* e2v = (const float4*)(emb + ((size_t)b * 4 + 2) * N);
    const float4* e3v = (const float4*)(emb + ((size_t)b * 4 + 3) * N);

    const int g0 = wb * 256 + tid;
    const int g1 = g0 + QSTRIDE;

    const int4   ivA = iv4[g0], ivB = iv4[g1];
    const float4 tvA = tv4[g0], tvB = tv4[g1];
    const float4 a0A = e0v[g0], a0B = e0v[g1];
    const float4 a1A = e1v[g0], a1B = e1v[g1];
    const float4 a2A = e2v[g0], a2B = e2v[g1];
    const float4 a3A = e3v[g0], a3B = e3v[g1];

    #define ACC2(iv, tv, a0, a1, a2, a3, px)                                   \
        {                                                                      \
            const int lab = (tv.px > 0.5f) ? iv.px : 0;                        \
            if (lab > 0) {                                                     \
                const float4 mu = s_mean[lab];                                 \
                const float dx = a0.px - mu.x;                                 \
                const float dy = a1.px - mu.y;                                 \
                const float dz = a2.px - mu.z;                                 \
                const float dw = a3.px - mu.w;                                 \
                const float dist = sqrtf(dx*dx + dy*dy + dz*dz + dw*dw);       \
                const float r   = fmaxf(dist - DELTA_V, 0.f);                  \
                const float val = logf(fmaf(r, r, 1.f));                       \
                float* p = &s_h[(lab - 1) * 34 + copy];                        \
                atomicAdd(p,      val);                                        \
                atomicAdd(p + 17, 1.f);                                        \
            }                                                                  \
        }
    ACC2(ivA, tvA, a0A, a1A, a2A, a3A, x)
    ACC2(ivA, tvA, a0A, a1A, a2A, a3A, y)
    ACC2(ivA, tvA, a0A, a1A, a2A, a3A, z)
    ACC2(ivA, tvA, a0A, a1A, a2A, a3A, w)
    ACC2(ivB, tvB, a0B, a1B, a2B, a3B, x)
    ACC2(ivB, tvB, a0B, a1B, a2B, a3B, y)
    ACC2(ivB, tvB, a0B, a1B, a2B, a3B, z)
    ACC2(ivB, tvB, a0B, a1B, a2B, a3B, w)
    #undef ACC2

    __syncthreads();

    if (tid < 32) {
        float s = 0.f;
        if (tid < 30) {
            #pragma unroll
            for (int c = 0; c < 16; ++c) s += s_h[tid * 17 + c];
        }
        stage2[b * 6400 + tid * 200 + wb] = s;    // distinct slot, plain store
    }
}

// ---------------------------------------------------------------------------
// finalize: reduce stage2 (240 rows x 200, coalesced + butterfly), then
// agg/pairwise/reg -> scalar.
// ---------------------------------------------------------------------------
__global__ __launch_bounds__(256) void finalize_kernel(
    const float* __restrict__ stage2, const float* __restrict__ meanv,
    float* __restrict__ out)
{
    __shared__ float rs2[240];      // [8][30]
    __shared__ float sm[512];       // meanv copy [8][16][4]
    __shared__ float s_part[128];

    const int tid = threadIdx.x;
    const int w = tid >> 6, lane = tid & 63;

    for (int r = w; r < 240; r += 4) {
        const int bb = r / 30, rr = r % 30;
        const float* p = stage2 + bb * 6400 + rr * 200;
        float s = 0.f;
        for (int j = lane; j < 200; j += 64) s += p[j];
        #pragma unroll
        for (int m = 32; m > 0; m >>= 1) s += __shfl_xor(s, m, 64);
        if (lane == 0) rs2[r] = s;
    }
    sm[tid]       = meanv[tid];
    sm[tid + 256] = meanv[tid + 256];
    __syncthreads();

    if (tid < 128) {                        // tid = bb*16 + k
        const int bb = tid >> 4, k = tid & 15;
        const float m0 = sm[tid * 4 + 0], m1 = sm[tid * 4 + 1];
        const float m2 = sm[tid * 4 + 2], m3 = sm[tid * 4 + 3];
        float partial = 0.f;

        if (k >= 1) {
            const float vs = rs2[bb * 30 + (k - 1) * 2 + 0];
            const float vc = rs2[bb * 30 + (k - 1) * 2 + 1];
            partial += (vs / fmaxf(vc, 1.f)) / 15.f;
        }
        if (k >= 1) {
            #pragma unroll
            for (int j = 1; j < NUM_K; ++j) {
                if (j == k) continue;
                const float dx = m0 - sm[(bb * 16 + j) * 4 + 0];
                const float dy = m1 - sm[(bb * 16 + j) * 4 + 1];
                const float dz = m2 - sm[(bb * 16 + j) * 4 + 2];
                const float dw = m3 - sm[(bb * 16 + j) * 4 + 3];
                const float pd = sqrtf(dx*dx + dy*dy + dz*dz + dw*dw);
                const float r  = fmaxf(2.f * DELTA_D - pd, 0.f);
                partial += logf(r * r + 1.f) / 210.f;
            }
        }
        {
            const float nrm = sqrtf(m0*m0 + m1*m1 + m2*m2 + m3*m3);
            partial += logf(nrm + 1.f) * (0.001f / 16.f);
        }
        s_part[tid] = partial;
    }
    __syncthreads();

    if (tid == 0) {
        float s = 0.f;
        for (int i = 0; i < 128; ++i) s += s_part[i];
        out[0] = s / 8.f;
    }
}

extern "C" void kernel_launch(void* const* d_in, const int* in_sizes, int n_in,
                              void* d_out, int out_size, void* d_ws, size_t ws_size,
                              hipStream_t stream) {
    const float* emb   = (const float*)d_in[0];
    const int*   inst  = (const int*)d_in[1];
    const float* kern  = (const float*)d_in[2];
    const float* tmask = (const float*)d_in[3];
    // d_in[4] = bboxes, unused

    const int N = in_sizes[1] / 8;      // 409600

    float* ws     = (float*)d_ws;
    float* stage1 = ws + S1OFF;
    float* stage2 = ws + S2OFF;
    float* meanv  = ws + MVOFF;
    float* outf   = (float*)d_out;

    pass1_kernel<<<dim3(BPB * 8), dim3(256), 0, stream>>>(
        emb, inst, kern, tmask, stage1, N);
    reduce_means_kernel<<<dim3(8), dim3(256), 0, stream>>>(stage1, meanv);
    pass2_kernel<<<dim3(BPB * 8), dim3(256), 0, stream>>>(
        emb, inst, tmask, meanv, stage2, N);
    finalize_kernel<<<dim3(1), dim3(256), 0, stream>>>(stage2, meanv, outf);
}

// Round 12
// 207.455 us; speedup vs baseline: 1.1435x; 1.1435x over previous
//
#include <hip/hip_runtime.h>
#include <math.h>

#define NUM_K 16
#define DELTA_V 0.5f
#define DELTA_D 1.5f

// B=8, N=640*640=409600 px/batch, ng=102400 quads/batch.
#define BPB 200
#define QSTRIDE (BPB * 256)

// ws layout (floats), all fully overwritten every launch (no memset):
//   stage1  @ 0      : [640][200]  (= [8][80][200]) pass1 per-block partials
//   stage2  @ 128000 : [256][200]  (= [8][32][200]) pass2 per-block partials
//   rowsum1 @ 179200 : [640]
//   rowsum2 @ 179840 : [256]
//   probe   @ 180224 : [409600]
#define S1OFF 0
#define S2OFF 128000
#define R1OFF 179200
#define R2OFF 179840
#define PROFF 180224

// ---------------------------------------------------------------------------
// pass1: 16-copy privatized LDS histogram; plain-store flush to staging.
// ---------------------------------------------------------------------------
__global__ __launch_bounds__(256) void pass1_kernel(
    const float* __restrict__ emb, const int* __restrict__ inst,
    const float* __restrict__ kern, const float* __restrict__ tmask,
    float* __restrict__ stage1, int N)
{
    __shared__ float s_h[75 * 17];
    for (int i = threadIdx.x; i < 75 * 17; i += 256) s_h[i] = 0.f;
    __syncthreads();

    const int tid  = threadIdx.x;
    const int b    = blockIdx.x / BPB;
    const int wb   = blockIdx.x % BPB;
    const int copy = tid & 15;

    const size_t base = (size_t)b * N;
    const int4*   iv4 = (const int4*)(inst + base);
    const float4* kv4 = (const float4*)(kern + base);
    const float4* tv4 = (const float4*)(tmask + base);
    const float4* e0v = (const float4*)(emb + ((size_t)b * 4 + 0) * N);
    const float4* e1v = (const float4*)(emb + ((size_t)b * 4 + 1) * N);
    const float4* e2v = (const float4*)(emb + ((size_t)b * 4 + 2) * N);
    const float4* e3v = (const float4*)(emb + ((size_t)b * 4 + 3) * N);

    const int g0 = wb * 256 + tid;
    const int g1 = g0 + QSTRIDE;

    const int4   ivA = iv4[g0], ivB = iv4[g1];
    const float4 kvA = kv4[g0], kvB = kv4[g1];
    const float4 tvA = tv4[g0], tvB = tv4[g1];
    const float4 a0A = e0v[g0], a0B = e0v[g1];
    const float4 a1A = e1v[g0], a1B = e1v[g1];
    const float4 a2A = e2v[g0], a2B = e2v[g1];
    const float4 a3A = e3v[g0], a3B = e3v[g1];

    #define ACC1(iv, kv, tv, a0, a1, a2, a3, px)                               \
        {                                                                      \
            const int lab = iv.px;                                             \
            if (lab > 0 && tv.px > 0.5f && kv.px > 0.5f) {                     \
                float* p = &s_h[(lab - 1) * 85 + copy];                        \
                atomicAdd(p +  0, a0.px);                                      \
                atomicAdd(p + 17, a1.px);                                      \
                atomicAdd(p + 34, a2.px);                                      \
                atomicAdd(p + 51, a3.px);                                      \
                atomicAdd(p + 68, 1.f);                                        \
            }                                                                  \
        }
    ACC1(ivA, kvA, tvA, a0A, a1A, a2A, a3A, x)
    ACC1(ivA, kvA, tvA, a0A, a1A, a2A, a3A, y)
    ACC1(ivA, kvA, tvA, a0A, a1A, a2A, a3A, z)
    ACC1(ivA, kvA, tvA, a0A, a1A, a2A, a3A, w)
    ACC1(ivB, kvB, tvB, a0B, a1B, a2B, a3B, x)
    ACC1(ivB, kvB, tvB, a0B, a1B, a2B, a3B, y)
    ACC1(ivB, kvB, tvB, a0B, a1B, a2B, a3B, z)
    ACC1(ivB, kvB, tvB, a0B, a1B, a2B, a3B, w)
    #undef ACC1

    __syncthreads();

    if (tid < 80) {
        float s = 0.f;
        if (tid < 75) {
            #pragma unroll
            for (int c = 0; c < 16; ++c) s += s_h[tid * 17 + c];
        }
        stage1[b * 16000 + tid * 200 + wb] = s;
    }
}

// ---------------------------------------------------------------------------
// rowsum: one WAVE per row of [nrows][200]; 4 independent loads + butterfly.
// Replaces the latency-serialized single/8-block reducers (72-79us measured).
// ---------------------------------------------------------------------------
__global__ __launch_bounds__(64) void rowsum_kernel(
    const float* __restrict__ src, float* __restrict__ dst)
{
    const int r    = blockIdx.x;
    const int lane = threadIdx.x;
    const float* p = src + (size_t)r * 200;

    float s = p[lane] + p[lane + 64] + p[lane + 128];   // 191 < 200: all valid
    if (lane < 8) s += p[lane + 192];
    #pragma unroll
    for (int m = 32; m > 0; m >>= 1) s += __shfl_xor(s, m, 64);
    if (lane == 0) dst[r] = s;
}

// ---------------------------------------------------------------------------
// pass2: distance-to-mean binning; means rebuilt from rowsum1 (80 floats).
// ---------------------------------------------------------------------------
__global__ __launch_bounds__(256) void pass2_kernel(
    const float* __restrict__ emb, const int* __restrict__ inst,
    const float* __restrict__ tmask, const float* __restrict__ rowsum1,
    float* __restrict__ stage2, int N)
{
    __shared__ float  s_h[30 * 17];
    __shared__ float  s_rs[80];
    __shared__ float4 s_mean[NUM_K];

    for (int i = threadIdx.x; i < 30 * 17; i += 256) s_h[i] = 0.f;

    const int tid = threadIdx.x;
    const int b   = blockIdx.x / BPB;
    const int wb  = blockIdx.x % BPB;

    if (tid < 80) s_rs[tid] = rowsum1[b * 80 + tid];
    __syncthreads();
    if (tid < 64) {
        const int k = tid >> 2, d = tid & 3;
        const float m = (k == 0) ? 0.f
            : s_rs[(k - 1) * 5 + d] / fmaxf(s_rs[(k - 1) * 5 + 4], 1.f);
        ((float*)&s_mean[k])[d] = m;
    }
    __syncthreads();

    const int copy = tid & 15;

    const size_t base = (size_t)b * N;
    const int4*   iv4 = (const int4*)(inst + base);
    const float4* tv4 = (const float4*)(tmask + base);
    const float4* e0v = (const float4*)(emb + ((size_t)b * 4 + 0) * N);
    const float4* e1v = (const float4*)(emb + ((size_t)b * 4 + 1) * N);
    const float4* e2v = (const float4*)(emb + ((size_t)b * 4 + 2) * N);
    const float4* e3v = (const float4*)(emb + ((size_t)b * 4 + 3) * N);

    const int g0 = wb * 256 + tid;
    const int g1 = g0 + QSTRIDE;

    const int4   ivA = iv4[g0], ivB = iv4[g1];
    const float4 tvA = tv4[g0], tvB = tv4[g1];
    const float4 a0A = e0v[g0], a0B = e0v[g1];
    const float4 a1A = e1v[g0], a1B = e1v[g1];
    const float4 a2A = e2v[g0], a2B = e2v[g1];
    const float4 a3A = e3v[g0], a3B = e3v[g1];

    #define ACC2(iv, tv, a0, a1, a2, a3, px)                                   \
        {                                                                      \
            const int lab = (tv.px > 0.5f) ? iv.px : 0;                        \
            if (lab > 0) {                                                     \
                const float4 mu = s_mean[lab];                                 \
                const float dx = a0.px - mu.x;                                 \
                const float dy = a1.px - mu.y;                                 \
                const float dz = a2.px - mu.z;                                 \
                const float dw = a3.px - mu.w;                                 \
                const float dist = sqrtf(dx*dx + dy*dy + dz*dz + dw*dw);       \
                const float r   = fmaxf(dist - DELTA_V, 0.f);                  \
                const float val = logf(fmaf(r, r, 1.f));                       \
                float* p = &s_h[(lab - 1) * 34 + copy];                        \
                atomicAdd(p,      val);                                        \
                atomicAdd(p + 17, 1.f);                                        \
            }                                                                  \
        }
    ACC2(ivA, tvA, a0A, a1A, a2A, a3A, x)
    ACC2(ivA, tvA, a0A, a1A, a2A, a3A, y)
    ACC2(ivA, tvA, a0A, a1A, a2A, a3A, z)
    ACC2(ivA, tvA, a0A, a1A, a2A, a3A, w)
    ACC2(ivB, tvB, a0B, a1B, a2B, a3B, x)
    ACC2(ivB, tvB, a0B, a1B, a2B, a3B, y)
    ACC2(ivB, tvB, a0B, a1B, a2B, a3B, z)
    ACC2(ivB, tvB, a0B, a1B, a2B, a3B, w)
    #undef ACC2

    __syncthreads();

    if (tid < 32) {
        float s = 0.f;
        if (tid < 30) {
            #pragma unroll
            for (int c = 0; c < 16; ++c) s += s_h[tid * 17 + c];
        }
        stage2[b * 6400 + tid * 200 + wb] = s;
    }
}

// ---------------------------------------------------------------------------
// final: 1 block, 128 thr; reads rowsum1[640] + rowsum2[256] (~3.5 KB only).
// ---------------------------------------------------------------------------
__global__ __launch_bounds__(128) void final_kernel(
    const float* __restrict__ rowsum1, const float* __restrict__ rowsum2,
    float* __restrict__ out)
{
    __shared__ float s_rs1[640];
    __shared__ float s_rs2[256];
    __shared__ float s_m[512];
    __shared__ float s_part[128];

    const int tid = threadIdx.x;

    #pragma unroll
    for (int i = 0; i < 5; ++i) s_rs1[tid + i * 128] = rowsum1[tid + i * 128];
    s_rs2[tid]       = rowsum2[tid];
    s_rs2[tid + 128] = rowsum2[tid + 128];
    __syncthreads();

    {   // means: tid = b*16 + k
        const int b = tid >> 4, k = tid & 15;
        float m0 = 0.f, m1 = 0.f, m2 = 0.f, m3 = 0.f;
        if (k != 0) {
            const float c   = s_rs1[b * 80 + (k - 1) * 5 + 4];
            const float inv = 1.f / fmaxf(c, 1.f);
            m0 = s_rs1[b * 80 + (k - 1) * 5 + 0] * inv;
            m1 = s_rs1[b * 80 + (k - 1) * 5 + 1] * inv;
            m2 = s_rs1[b * 80 + (k - 1) * 5 + 2] * inv;
            m3 = s_rs1[b * 80 + (k - 1) * 5 + 3] * inv;
        }
        s_m[tid * 4 + 0] = m0; s_m[tid * 4 + 1] = m1;
        s_m[tid * 4 + 2] = m2; s_m[tid * 4 + 3] = m3;
    }
    __syncthreads();

    {
        const int b = tid >> 4, k = tid & 15;
        const float m0 = s_m[tid * 4 + 0], m1 = s_m[tid * 4 + 1];
        const float m2 = s_m[tid * 4 + 2], m3 = s_m[tid * 4 + 3];
        float partial = 0.f;

        if (k >= 1) {
            const float vs = s_rs2[b * 32 + (k - 1) * 2 + 0];
            const float vc = s_rs2[b * 32 + (k - 1) * 2 + 1];
            partial += (vs / fmaxf(vc, 1.f)) / 15.f;
        }
        if (k >= 1) {
            #pragma unroll
            for (int j = 1; j < NUM_K; ++j) {
                if (j == k) continue;
                const float dx = m0 - s_m[(b * 16 + j) * 4 + 0];
                const float dy = m1 - s_m[(b * 16 + j) * 4 + 1];
                const float dz = m2 - s_m[(b * 16 + j) * 4 + 2];
                const float dw = m3 - s_m[(b * 16 + j) * 4 + 3];
                const float pd = sqrtf(dx*dx + dy*dy + dz*dz + dw*dw);
                const float r  = fmaxf(2.f * DELTA_D - pd, 0.f);
                partial += logf(r * r + 1.f) / 210.f;
            }
        }
        {
            const float nrm = sqrtf(m0*m0 + m1*m1 + m2*m2 + m3*m3);
            partial += logf(nrm + 1.f) * (0.001f / 16.f);
        }
        s_part[tid] = partial;
    }
    __syncthreads();

    if (tid == 0) {
        float s = 0.f;
        for (int i = 0; i < 128; ++i) s += s_part[i];
        out[0] = s / 8.f;
    }
}

// ---------------------------------------------------------------------------
// DIAGNOSTIC probe: pass1's exact 14-load pattern, 4 rotated sweeps, no
// histogram. Runs LAST (L3-warm). Per-sweep time = pure load floor.
// ---------------------------------------------------------------------------
__global__ __launch_bounds__(256) void probe_load4_kernel(
    const float* __restrict__ emb, const int* __restrict__ inst,
    const float* __restrict__ kern, const float* __restrict__ tmask,
    float* __restrict__ scratch, int N)
{
    const int tid = threadIdx.x;
    const int b   = blockIdx.x / BPB;
    const int wb0 = blockIdx.x % BPB;

    const size_t base = (size_t)b * N;
    const int4*   iv4 = (const int4*)(inst + base);
    const float4* kv4 = (const float4*)(kern + base);
    const float4* tv4 = (const float4*)(tmask + base);
    const float4* e0v = (const float4*)(emb + ((size_t)b * 4 + 0) * N);
    const float4* e1v = (const float4*)(emb + ((size_t)b * 4 + 1) * N);
    const float4* e2v = (const float4*)(emb + ((size_t)b * 4 + 2) * N);
    const float4* e3v = (const float4*)(emb + ((size_t)b * 4 + 3) * N);

    float acc = 0.f;
    #pragma unroll
    for (int t = 0; t < 4; ++t) {
        const int wb = (wb0 + t * 53) % BPB;
        const int g0 = wb * 256 + tid;
        const int g1 = g0 + QSTRIDE;

        const int4   ivA = iv4[g0], ivB = iv4[g1];
        const float4 kvA = kv4[g0], kvB = kv4[g1];
        const float4 tvA = tv4[g0], tvB = tv4[g1];
        const float4 a0A = e0v[g0], a0B = e0v[g1];
        const float4 a1A = e1v[g0], a1B = e1v[g1];
        const float4 a2A = e2v[g0], a2B = e2v[g1];
        const float4 a3A = e3v[g0], a3B = e3v[g1];

        acc += (float)(ivA.x + ivA.y + ivA.z + ivA.w)
             + (float)(ivB.x + ivB.y + ivB.z + ivB.w)
             + kvA.x + kvA.y + kvA.z + kvA.w
             + kvB.x + kvB.y + kvB.z + kvB.w
             + tvA.x + tvA.y + tvA.z + tvA.w
             + tvB.x + tvB.y + tvB.z + tvB.w
             + a0A.x + a0A.y + a0A.z + a0A.w + a0B.x + a0B.y + a0B.z + a0B.w
             + a1A.x + a1A.y + a1A.z + a1A.w + a1B.x + a1B.y + a1B.z + a1B.w
             + a2A.x + a2A.y + a2A.z + a2A.w + a2B.x + a2B.y + a2B.z + a2B.w
             + a3A.x + a3A.y + a3A.z + a3A.w + a3B.x + a3B.y + a3B.z + a3B.w;
    }
    scratch[blockIdx.x * 256 + tid] = acc;
}

extern "C" void kernel_launch(void* const* d_in, const int* in_sizes, int n_in,
                              void* d_out, int out_size, void* d_ws, size_t ws_size,
                              hipStream_t stream) {
    const float* emb   = (const float*)d_in[0];
    const int*   inst  = (const int*)d_in[1];
    const float* kern  = (const float*)d_in[2];
    const float* tmask = (const float*)d_in[3];
    // d_in[4] = bboxes, unused

    const int N = in_sizes[1] / 8;      // 409600

    float* ws      = (float*)d_ws;
    float* stage1  = ws + S1OFF;
    float* stage2  = ws + S2OFF;
    float* rowsum1 = ws + R1OFF;
    float* rowsum2 = ws + R2OFF;
    float* probes  = ws + PROFF;
    float* outf    = (float*)d_out;

    pass1_kernel<<<dim3(BPB * 8), dim3(256), 0, stream>>>(
        emb, inst, kern, tmask, stage1, N);
    rowsum_kernel<<<dim3(640), dim3(64), 0, stream>>>(stage1, rowsum1);
    pass2_kernel<<<dim3(BPB * 8), dim3(256), 0, stream>>>(
        emb, inst, tmask, rowsum1, stage2, N);
    rowsum_kernel<<<dim3(256), dim3(64), 0, stream>>>(stage2, rowsum2);
    final_kernel<<<dim3(1), dim3(128), 0, stream>>>(rowsum1, rowsum2, outf);
    probe_load4_kernel<<<dim3(BPB * 8), dim3(256), 0, stream>>>(
        emb, inst, kern, tmask, probes, N);
}

// Round 14
// 165.649 us; speedup vs baseline: 1.4321x; 1.2524x over previous
//
#include <hip/hip_runtime.h>
#include <math.h>

#define NUM_K 16
#define DELTA_V 0.5f
#define DELTA_D 1.5f

// B=8, N=640*640=409600 px/batch, ng=102400 quads/batch.
// Grid: 100 blocks/batch x 8 = 800 blocks, 256 thr, 4 quads/thread.
// All loads issued up-front (28 resp. 24 deep) before any LDS work.
#define BPB 100
#define QS  (BPB * 256)          // 25600 quads covered per sweep step

// ws layout (floats), all fully overwritten every launch (no memset):
//   stage1  @ 0     : [8][80][100]
//   stage2  @ 64000 : [8][32][100]
//   rowsum1 @ 89600 : [640]
//   rowsum2 @ 90240 : [256]
#define S1OFF 0
#define S2OFF 64000
#define R1OFF 89600
#define R2OFF 90240

// ---------------------------------------------------------------------------
// pass1: 16-copy privatized LDS histogram; 28 loads batched up-front.
// ---------------------------------------------------------------------------
__global__ __launch_bounds__(256, 2) void pass1_kernel(
    const float* __restrict__ emb, const int* __restrict__ inst,
    const float* __restrict__ kern, const float* __restrict__ tmask,
    float* __restrict__ stage1, int N)
{
    __shared__ float s_h[75 * 17];
    for (int i = threadIdx.x; i < 75 * 17; i += 256) s_h[i] = 0.f;
    __syncthreads();

    const int tid  = threadIdx.x;
    const int b    = blockIdx.x / BPB;
    const int wb   = blockIdx.x % BPB;
    const int copy = tid & 15;

    const size_t base = (size_t)b * N;
    const int4*   iv4 = (const int4*)(inst + base);
    const float4* kv4 = (const float4*)(kern + base);
    const float4* tv4 = (const float4*)(tmask + base);
    const float4* e0v = (const float4*)(emb + ((size_t)b * 4 + 0) * N);
    const float4* e1v = (const float4*)(emb + ((size_t)b * 4 + 1) * N);
    const float4* e2v = (const float4*)(emb + ((size_t)b * 4 + 2) * N);
    const float4* e3v = (const float4*)(emb + ((size_t)b * 4 + 3) * N);

    const int g = wb * 256 + tid;            // + s*QS, s=0..3

    // ---- issue all 28 loads before any use ----
    const int4   iq0 = iv4[g], iq1 = iv4[g + QS], iq2 = iv4[g + 2 * QS], iq3 = iv4[g + 3 * QS];
    const float4 kq0 = kv4[g], kq1 = kv4[g + QS], kq2 = kv4[g + 2 * QS], kq3 = kv4[g + 3 * QS];
    const float4 tq0 = tv4[g], tq1 = tv4[g + QS], tq2 = tv4[g + 2 * QS], tq3 = tv4[g + 3 * QS];
    const float4 p0q0 = e0v[g], p0q1 = e0v[g + QS], p0q2 = e0v[g + 2 * QS], p0q3 = e0v[g + 3 * QS];
    const float4 p1q0 = e1v[g], p1q1 = e1v[g + QS], p1q2 = e1v[g + 2 * QS], p1q3 = e1v[g + 3 * QS];
    const float4 p2q0 = e2v[g], p2q1 = e2v[g + QS], p2q2 = e2v[g + 2 * QS], p2q3 = e2v[g + 3 * QS];
    const float4 p3q0 = e3v[g], p3q1 = e3v[g + QS], p3q2 = e3v[g + 2 * QS], p3q3 = e3v[g + 3 * QS];

    #define ACC1(iv, kv, tv, a0, a1, a2, a3, px)                               \
        {                                                                      \
            const int lab = iv.px;                                             \
            if (lab > 0 && tv.px > 0.5f && kv.px > 0.5f) {                     \
                float* p = &s_h[(lab - 1) * 85 + copy];                        \
                atomicAdd(p +  0, a0.px);                                      \
                atomicAdd(p + 17, a1.px);                                      \
                atomicAdd(p + 34, a2.px);                                      \
                atomicAdd(p + 51, a3.px);                                      \
                atomicAdd(p + 68, 1.f);                                        \
            }                                                                  \
        }
    #define QUAD1(iq, kq, tq, a0, a1, a2, a3)                                  \
        ACC1(iq, kq, tq, a0, a1, a2, a3, x)                                    \
        ACC1(iq, kq, tq, a0, a1, a2, a3, y)                                    \
        ACC1(iq, kq, tq, a0, a1, a2, a3, z)                                    \
        ACC1(iq, kq, tq, a0, a1, a2, a3, w)

    QUAD1(iq0, kq0, tq0, p0q0, p1q0, p2q0, p3q0)
    QUAD1(iq1, kq1, tq1, p0q1, p1q1, p2q1, p3q1)
    QUAD1(iq2, kq2, tq2, p0q2, p1q2, p2q2, p3q2)
    QUAD1(iq3, kq3, tq3, p0q3, p1q3, p2q3, p3q3)
    #undef QUAD1
    #undef ACC1

    __syncthreads();

    if (tid < 80) {
        float s = 0.f;
        if (tid < 75) {
            #pragma unroll
            for (int c = 0; c < 16; ++c) s += s_h[tid * 17 + c];
        }
        stage1[b * 8000 + tid * 100 + wb] = s;
    }
}

// ---------------------------------------------------------------------------
// rowsum: one WAVE per row of [nrows][100]; parallel, no serialization.
// ---------------------------------------------------------------------------
__global__ __launch_bounds__(64) void rowsum_kernel(
    const float* __restrict__ src, float* __restrict__ dst)
{
    const int r    = blockIdx.x;
    const int lane = threadIdx.x;
    const float* p = src + (size_t)r * 100;

    float s = p[lane];
    if (lane < 36) s += p[lane + 64];
    #pragma unroll
    for (int m = 32; m > 0; m >>= 1) s += __shfl_xor(s, m, 64);
    if (lane == 0) dst[r] = s;
}

// ---------------------------------------------------------------------------
// pass2: distance-to-mean binning; 24 loads batched up-front.
// ---------------------------------------------------------------------------
__global__ __launch_bounds__(256, 2) void pass2_kernel(
    const float* __restrict__ emb, const int* __restrict__ inst,
    const float* __restrict__ tmask, const float* __restrict__ rowsum1,
    float* __restrict__ stage2, int N)
{
    __shared__ float  s_h[30 * 17];
    __shared__ float  s_rs[80];
    __shared__ float4 s_mean[NUM_K];

    for (int i = threadIdx.x; i < 30 * 17; i += 256) s_h[i] = 0.f;

    const int tid = threadIdx.x;
    const int b   = blockIdx.x / BPB;
    const int wb  = blockIdx.x % BPB;

    if (tid < 80) s_rs[tid] = rowsum1[b * 80 + tid];
    __syncthreads();
    if (tid < 64) {
        const int k = tid >> 2, d = tid & 3;
        const float m = (k == 0) ? 0.f
            : s_rs[(k - 1) * 5 + d] / fmaxf(s_rs[(k - 1) * 5 + 4], 1.f);
        ((float*)&s_mean[k])[d] = m;
    }
    __syncthreads();

    const int copy = tid & 15;

    const size_t base = (size_t)b * N;
    const int4*   iv4 = (const int4*)(inst + base);
    const float4* tv4 = (const float4*)(tmask + base);
    const float4* e0v = (const float4*)(emb + ((size_t)b * 4 + 0) * N);
    const float4* e1v = (const float4*)(emb + ((size_t)b * 4 + 1) * N);
    const float4* e2v = (const float4*)(emb + ((size_t)b * 4 + 2) * N);
    const float4* e3v = (const float4*)(emb + ((size_t)b * 4 + 3) * N);

    const int g = wb * 256 + tid;

    const int4   iq0 = iv4[g], iq1 = iv4[g + QS], iq2 = iv4[g + 2 * QS], iq3 = iv4[g + 3 * QS];
    const float4 tq0 = tv4[g], tq1 = tv4[g + QS], tq2 = tv4[g + 2 * QS], tq3 = tv4[g + 3 * QS];
    const float4 p0q0 = e0v[g], p0q1 = e0v[g + QS], p0q2 = e0v[g + 2 * QS], p0q3 = e0v[g + 3 * QS];
    const float4 p1q0 = e1v[g], p1q1 = e1v[g + QS], p1q2 = e1v[g + 2 * QS], p1q3 = e1v[g + 3 * QS];
    const float4 p2q0 = e2v[g], p2q1 = e2v[g + QS], p2q2 = e2v[g + 2 * QS], p2q3 = e2v[g + 3 * QS];
    const float4 p3q0 = e3v[g], p3q1 = e3v[g + QS], p3q2 = e3v[g + 2 * QS], p3q3 = e3v[g + 3 * QS];

    #define ACC2(iv, tv, a0, a1, a2, a3, px)                                   \
        {                                                                      \
            const int lab = (tv.px > 0.5f) ? iv.px : 0;                        \
            if (lab > 0) {                                                     \
                const float4 mu = s_mean[lab];                                 \
                const float dx = a0.px - mu.x;                                 \
                const float dy = a1.px - mu.y;                                 \
                const float dz = a2.px - mu.z;                                 \
                const float dw = a3.px - mu.w;                                 \
                const float dist = sqrtf(dx*dx + dy*dy + dz*dz + dw*dw);       \
                const float r   = fmaxf(dist - DELTA_V, 0.f);                  \
                const float val = logf(fmaf(r, r, 1.f));                       \
                float* p = &s_h[(lab - 1) * 34 + copy];                        \
                atomicAdd(p,      val);                                        \
                atomicAdd(p + 17, 1.f);                                        \
            }                                                                  \
        }
    #define QUAD2(iq, tq, a0, a1, a2, a3)                                      \
        ACC2(iq, tq, a0, a1, a2, a3, x)                                        \
        ACC2(iq, tq, a0, a1, a2, a3, y)                                        \
        ACC2(iq, tq, a0, a1, a2, a3, z)                                        \
        ACC2(iq, tq, a0, a1, a2, a3, w)

    QUAD2(iq0, tq0, p0q0, p1q0, p2q0, p3q0)
    QUAD2(iq1, tq1, p0q1, p1q1, p2q1, p3q1)
    QUAD2(iq2, tq2, p0q2, p1q2, p2q2, p3q2)
    QUAD2(iq3, tq3, p0q3, p1q3, p2q3, p3q3)
    #undef QUAD2
    #undef ACC2

    __syncthreads();

    if (tid < 32) {
        float s = 0.f;
        if (tid < 30) {
            #pragma unroll
            for (int c = 0; c < 16; ++c) s += s_h[tid * 17 + c];
        }
        stage2[b * 3200 + tid * 100 + wb] = s;
    }
}

// ---------------------------------------------------------------------------
// final: 1 block, 128 thr; reads rowsum1[640] + rowsum2[256] (~3.5 KB).
// ---------------------------------------------------------------------------
__global__ __launch_bounds__(128) void final_kernel(
    const float* __restrict__ rowsum1, const float* __restrict__ rowsum2,
    float* __restrict__ out)
{
    __shared__ float s_rs1[640];
    __shared__ float s_rs2[256];
    __shared__ float s_m[512];
    __shared__ float s_part[128];

    const int tid = threadIdx.x;

    #pragma unroll
    for (int i = 0; i < 5; ++i) s_rs1[tid + i * 128] = rowsum1[tid + i * 128];
    s_rs2[tid]       = rowsum2[tid];
    s_rs2[tid + 128] = rowsum2[tid + 128];
    __syncthreads();

    {   // means: tid = b*16 + k
        const int b = tid >> 4, k = tid & 15;
        float m0 = 0.f, m1 = 0.f, m2 = 0.f, m3 = 0.f;
        if (k != 0) {
            const float c   = s_rs1[b * 80 + (k - 1) * 5 + 4];
            const float inv = 1.f / fmaxf(c, 1.f);
            m0 = s_rs1[b * 80 + (k - 1) * 5 + 0] * inv;
            m1 = s_rs1[b * 80 + (k - 1) * 5 + 1] * inv;
            m2 = s_rs1[b * 80 + (k - 1) * 5 + 2] * inv;
            m3 = s_rs1[b * 80 + (k - 1) * 5 + 3] * inv;
        }
        s_m[tid * 4 + 0] = m0; s_m[tid * 4 + 1] = m1;
        s_m[tid * 4 + 2] = m2; s_m[tid * 4 + 3] = m3;
    }
    __syncthreads();

    {
        const int b = tid >> 4, k = tid & 15;
        const float m0 = s_m[tid * 4 + 0], m1 = s_m[tid * 4 + 1];
        const float m2 = s_m[tid * 4 + 2], m3 = s_m[tid * 4 + 3];
        float partial = 0.f;

        if (k >= 1) {
            const float vs = s_rs2[b * 32 + (k - 1) * 2 + 0];
            const float vc = s_rs2[b * 32 + (k - 1) * 2 + 1];
            partial += (vs / fmaxf(vc, 1.f)) / 15.f;
        }
        if (k >= 1) {
            #pragma unroll
            for (int j = 1; j < NUM_K; ++j) {
                if (j == k) continue;
                const float dx = m0 - s_m[(b * 16 + j) * 4 + 0];
                const float dy = m1 - s_m[(b * 16 + j) * 4 + 1];
                const float dz = m2 - s_m[(b * 16 + j) * 4 + 2];
                const float dw = m3 - s_m[(b * 16 + j) * 4 + 3];
                const float pd = sqrtf(dx*dx + dy*dy + dz*dz + dw*dw);
                const float r  = fmaxf(2.f * DELTA_D - pd, 0.f);
                partial += logf(r * r + 1.f) / 210.f;
            }
        }
        {
            const float nrm = sqrtf(m0*m0 + m1*m1 + m2*m2 + m3*m3);
            partial += logf(nrm + 1.f) * (0.001f / 16.f);
        }
        s_part[tid] = partial;
    }
    __syncthreads();

    if (tid == 0) {
        float s = 0.f;
        for (int i = 0; i < 128; ++i) s += s_part[i];
        out[0] = s / 8.f;
    }
}

extern "C" void kernel_launch(void* const* d_in, const int* in_sizes, int n_in,
                              void* d_out, int out_size, void* d_ws, size_t ws_size,
                              hipStream_t stream) {
    const float* emb   = (const float*)d_in[0];
    const int*   inst  = (const int*)d_in[1];
    const float* kern  = (const float*)d_in[2];
    const float* tmask = (const float*)d_in[3];
    // d_in[4] = bboxes, unused

    const int N = in_sizes[1] / 8;      // 409600

    float* ws      = (float*)d_ws;
    float* stage1  = ws + S1OFF;
    float* stage2  = ws + S2OFF;
    float* rowsum1 = ws + R1OFF;
    float* rowsum2 = ws + R2OFF;
    float* outf    = (float*)d_out;

    pass1_kernel<<<dim3(BPB * 8), dim3(256), 0, stream>>>(
        emb, inst, kern, tmask, stage1, N);
    rowsum_kernel<<<dim3(640), dim3(64), 0, stream>>>(stage1, rowsum1);
    pass2_kernel<<<dim3(BPB * 8), dim3(256), 0, stream>>>(
        emb, inst, tmask, rowsum1, stage2, N);
    rowsum_kernel<<<dim3(256), dim3(64), 0, stream>>>(stage2, rowsum2);
    final_kernel<<<dim3(1), dim3(128), 0, stream>>>(rowsum1, rowsum2, outf);
}